// Round 1
// baseline (82.455 us; speedup 1.0000x reference)
//
#include <hip/hip_runtime.h>

// 4-qubit statevector QNN. Round 4: 2 samples per thread (ILP + half the
// waves), layer-0 RY fused into input angles, final RY layer folded into the
// <Z> extraction, HW trig in revolutions, LDS-staged coalesced float4 output.

#define INV_2PI 0.15915494309189535f
#define SPT 2  // samples per thread

template <int MASK>
__device__ __forceinline__ void apply_ry(float st[16], float c, float s) {
#pragma unroll
    for (int i = 0; i < 16; ++i) {
        if (!(i & MASK)) {
            float a0 = st[i];
            float a1 = st[i | MASK];
            st[i]        = fmaf(c, a0, -s * a1);
            st[i | MASK] = fmaf(s, a0,  c * a1);
        }
    }
}

template <int CMASK, int TMASK>
__device__ __forceinline__ void apply_cnot(float st[16]) {
#pragma unroll
    for (int i = 0; i < 16; ++i) {
        if ((i & CMASK) && !(i & TMASK)) {
            float tmp     = st[i];
            st[i]         = st[i | TMASK];
            st[i | TMASK] = tmp;
        }
    }
}

__global__ __launch_bounds__(256) void qnn_kernel(
    const float* __restrict__ x,      // (B,4)
    const float* __restrict__ qw,     // (3,4)
    const float* __restrict__ W,      // (6,4)
    const float* __restrict__ bias,   // (6,)
    float* __restrict__ out,          // (B,6)
    int B)
{
    __shared__ float qw0[4];           // layer-0 raw angles (fused into x)
    __shared__ float c1h[4], s1h[4];   // layer-1 half-angle cos/sin
    __shared__ float c2f[4], s2n[4];   // layer-2 full-angle cos / (-2*sin)
    __shared__ float sW[24], sb[6];
    __shared__ float so[256 * SPT * 6];  // output staging (12 KiB)

    const int tid = threadIdx.x;
    if (tid < 4) {
        qw0[tid] = qw[tid];
        float r1 = qw[4 + tid] * (0.5f * INV_2PI);
        c1h[tid] = __builtin_amdgcn_cosf(r1);
        s1h[tid] = __builtin_amdgcn_sinf(r1);
        float r2 = qw[8 + tid] * INV_2PI;
        c2f[tid] = __builtin_amdgcn_cosf(r2);
        s2n[tid] = -2.0f * __builtin_amdgcn_sinf(r2);
    }
    if (tid < 24) sW[tid] = W[tid];
    if (tid < 6)  sb[tid] = bias[tid];
    __syncthreads();

    const long long blockBase = (long long)blockIdx.x * (256 * SPT);

    // --- global loads first (independent, issued back to back) ---
    float4 xv[SPT];
#pragma unroll
    for (int u = 0; u < SPT; ++u) {
        long long b = blockBase + u * 256 + tid;
        xv[u] = (b < B) ? reinterpret_cast<const float4*>(x)[b]
                        : make_float4(0.f, 0.f, 0.f, 0.f);
    }

    // --- trig + fused initial product state (16 independent trans ops) ---
    float st[SPT][16];
#pragma unroll
    for (int u = 0; u < SPT; ++u) {
        float r0 = (xv[u].x + qw0[0]) * (0.5f * INV_2PI);
        float r1 = (xv[u].y + qw0[1]) * (0.5f * INV_2PI);
        float r2 = (xv[u].z + qw0[2]) * (0.5f * INV_2PI);
        float r3 = (xv[u].w + qw0[3]) * (0.5f * INV_2PI);
        float c0 = __builtin_amdgcn_cosf(r0), s0 = __builtin_amdgcn_sinf(r0);
        float c1 = __builtin_amdgcn_cosf(r1), s1 = __builtin_amdgcn_sinf(r1);
        float c2 = __builtin_amdgcn_cosf(r2), s2 = __builtin_amdgcn_sinf(r2);
        float c3 = __builtin_amdgcn_cosf(r3), s3 = __builtin_amdgcn_sinf(r3);

        float a01[4] = { c0 * c1, c0 * s1, s0 * c1, s0 * s1 };  // bits 8,4
        float a23[4] = { c2 * c3, c2 * s3, s2 * c3, s2 * s3 };  // bits 2,1
#pragma unroll
        for (int hi = 0; hi < 4; ++hi)
#pragma unroll
            for (int lo = 0; lo < 4; ++lo)
                st[u][hi * 4 + lo] = a01[hi] * a23[lo];
    }

    // --- CNOT ring, layer-1 RY, CNOT ring (two independent streams) ---
#pragma unroll
    for (int u = 0; u < SPT; ++u) {
        apply_cnot<8, 4>(st[u]); apply_cnot<4, 2>(st[u]);
        apply_cnot<2, 1>(st[u]); apply_cnot<1, 8>(st[u]);

        apply_ry<8>(st[u], c1h[0], s1h[0]);
        apply_ry<4>(st[u], c1h[1], s1h[1]);
        apply_ry<2>(st[u], c1h[2], s1h[2]);
        apply_ry<1>(st[u], c1h[3], s1h[3]);

        apply_cnot<8, 4>(st[u]); apply_cnot<4, 2>(st[u]);
        apply_cnot<2, 1>(st[u]); apply_cnot<1, 8>(st[u]);
    }

    // --- layer-2 RY folded into <Z_w>, logits, softmax, LDS staging ---
#pragma unroll
    for (int u = 0; u < SPT; ++u) {
        float p[16];
#pragma unroll
        for (int i = 0; i < 16; ++i) p[i] = st[u][i] * st[u][i];

        float z[4];
#pragma unroll
        for (int w = 0; w < 4; ++w) {
            const int m = 8 >> w;
            float A1 = 0.0f, X = 0.0f;
#pragma unroll
            for (int i = 0; i < 16; ++i) {
                if (!(i & m)) {
                    A1 += p[i | m];
                    X  = fmaf(st[u][i], st[u][i | m], X);
                }
            }
            // z = cos(th)*(1-2*A1) + (-2*sin(th))*X
            z[w] = fmaf(s2n[w], X, c2f[w] * fmaf(-2.0f, A1, 1.0f));
        }

        float e[6];
        float sum = 0.0f;
#pragma unroll
        for (int j = 0; j < 6; ++j) {
            float a = sb[j];
            a = fmaf(z[0], sW[j * 4 + 0], a);
            a = fmaf(z[1], sW[j * 4 + 1], a);
            a = fmaf(z[2], sW[j * 4 + 2], a);
            a = fmaf(z[3], sW[j * 4 + 3], a);
            e[j] = __expf(a);
            sum += e[j];
        }
        const float inv = __builtin_amdgcn_rcpf(sum);

        const int slot = u * 256 + tid;
#pragma unroll
        for (int j = 0; j < 6; ++j) so[slot * 6 + j] = e[j] * inv;
    }
    __syncthreads();

    // --- fully-coalesced float4 stores: 768 float4 per block, 3 per thread ---
    const float4* so4 = reinterpret_cast<const float4*>(so);
    float4* out4 = reinterpret_cast<float4*>(out);
    const long long base   = (long long)blockIdx.x * (256 * SPT * 6 / 4);
    const long long total4 = (long long)B * 6 / 4;     // B*6 divisible by 4
#pragma unroll
    for (int k = 0; k < 3; ++k) {
        int idx = tid + k * 256;
        if (base + idx < total4)
            out4[base + idx] = so4[idx];
    }
}

extern "C" void kernel_launch(void* const* d_in, const int* in_sizes, int n_in,
                              void* d_out, int out_size, void* d_ws, size_t ws_size,
                              hipStream_t stream) {
    const float* x    = (const float*)d_in[0];   // (B,4)
    const float* qw   = (const float*)d_in[1];   // (3,4)
    const float* W    = (const float*)d_in[2];   // (6,4)
    const float* bias = (const float*)d_in[3];   // (6,)
    float* out = (float*)d_out;

    const int B = in_sizes[0] / 4;
    const int blocks = (B + 256 * SPT - 1) / (256 * SPT);
    qnn_kernel<<<blocks, 256, 0, stream>>>(x, qw, W, bias, out, B);
}

// Round 2
// 80.874 us; speedup vs baseline: 1.0195x; 1.0195x over previous
//
#include <hip/hip_runtime.h>

// 4-qubit statevector QNN. Round 5: occupancy-first. SPT=1,
// __launch_bounds__(256,8) to force <=64 VGPR (8 waves/SIMD); p[] array
// eliminated (on-the-fly S1 accumulation, -16 regs, -16 ops); int-only
// addressing. Layer-0 RY fused into input angles, final RY layer folded
// into <Z>, HW trig in revolutions, LDS-staged coalesced float4 output.

#define INV_2PI 0.15915494309189535f

template <int MASK>
__device__ __forceinline__ void apply_ry(float st[16], float c, float s) {
#pragma unroll
    for (int i = 0; i < 16; ++i) {
        if (!(i & MASK)) {
            float a0 = st[i];
            float a1 = st[i | MASK];
            st[i]        = fmaf(c, a0, -s * a1);
            st[i | MASK] = fmaf(s, a0,  c * a1);
        }
    }
}

template <int CMASK, int TMASK>
__device__ __forceinline__ void apply_cnot(float st[16]) {
#pragma unroll
    for (int i = 0; i < 16; ++i) {
        if ((i & CMASK) && !(i & TMASK)) {
            float tmp     = st[i];
            st[i]         = st[i | TMASK];
            st[i | TMASK] = tmp;
        }
    }
}

__global__ __launch_bounds__(256, 8) void qnn_kernel(
    const float* __restrict__ x,      // (B,4)
    const float* __restrict__ qw,     // (3,4)
    const float* __restrict__ W,      // (6,4)
    const float* __restrict__ bias,   // (6,)
    float* __restrict__ out,          // (B,6)
    int B)
{
    __shared__ float qw0[4];           // layer-0 raw angles (fused into x)
    __shared__ float c1h[4], s1h[4];   // layer-1 half-angle cos/sin
    __shared__ float c2f[4], s2n[4];   // layer-2 full-angle cos / (-2*sin)
    __shared__ float sW[24], sb[6];
    __shared__ float so[256 * 6];      // output staging (6 KiB)

    const int tid = threadIdx.x;
    if (tid < 4) {
        qw0[tid] = qw[tid];
        float r1 = qw[4 + tid] * (0.5f * INV_2PI);
        c1h[tid] = __builtin_amdgcn_cosf(r1);
        s1h[tid] = __builtin_amdgcn_sinf(r1);
        float r2 = qw[8 + tid] * INV_2PI;
        c2f[tid] = __builtin_amdgcn_cosf(r2);
        s2n[tid] = -2.0f * __builtin_amdgcn_sinf(r2);
    }
    if (tid < 24) sW[tid] = W[tid];
    if (tid < 6)  sb[tid] = bias[tid];
    __syncthreads();

    const int b = blockIdx.x * 256 + tid;  // B = 1e6 fits int comfortably
    float4 xv = (b < B) ? reinterpret_cast<const float4*>(x)[b]
                        : make_float4(0.f, 0.f, 0.f, 0.f);

    // Fused initial product state: half-angles (x_k + w0_k)/2
    float st[16];
    {
        float r0 = (xv.x + qw0[0]) * (0.5f * INV_2PI);
        float r1 = (xv.y + qw0[1]) * (0.5f * INV_2PI);
        float r2 = (xv.z + qw0[2]) * (0.5f * INV_2PI);
        float r3 = (xv.w + qw0[3]) * (0.5f * INV_2PI);
        float c0 = __builtin_amdgcn_cosf(r0), s0 = __builtin_amdgcn_sinf(r0);
        float c1 = __builtin_amdgcn_cosf(r1), s1 = __builtin_amdgcn_sinf(r1);
        float c2 = __builtin_amdgcn_cosf(r2), s2 = __builtin_amdgcn_sinf(r2);
        float c3 = __builtin_amdgcn_cosf(r3), s3 = __builtin_amdgcn_sinf(r3);

        float a01[4] = { c0 * c1, c0 * s1, s0 * c1, s0 * s1 };  // bits 8,4
        float a23[4] = { c2 * c3, c2 * s3, s2 * c3, s2 * s3 };  // bits 2,1
#pragma unroll
        for (int hi = 0; hi < 4; ++hi)
#pragma unroll
            for (int lo = 0; lo < 4; ++lo)
                st[hi * 4 + lo] = a01[hi] * a23[lo];
    }

    // CNOT ring (register renames), layer-1 RY, CNOT ring
    apply_cnot<8, 4>(st); apply_cnot<4, 2>(st);
    apply_cnot<2, 1>(st); apply_cnot<1, 8>(st);

    apply_ry<8>(st, c1h[0], s1h[0]);
    apply_ry<4>(st, c1h[1], s1h[1]);
    apply_ry<2>(st, c1h[2], s1h[2]);
    apply_ry<1>(st, c1h[3], s1h[3]);

    apply_cnot<8, 4>(st); apply_cnot<4, 2>(st);
    apply_cnot<2, 1>(st); apply_cnot<1, 8>(st);

    // Layer-2 RY folded into <Z_w>:
    //   z_w = cos(th)*(1 - 2*S1_w) + (-2*sin(th))*X_w
    // with S1_w = sum st[i|m]^2, X_w = sum st[i]*st[i|m]  (on the fly, no p[])
    float z[4];
#pragma unroll
    for (int w = 0; w < 4; ++w) {
        const int m = 8 >> w;
        float S1 = 0.0f, X = 0.0f;
#pragma unroll
        for (int i = 0; i < 16; ++i) {
            if (!(i & m)) {
                float hi = st[i | m];
                S1 = fmaf(hi, hi, S1);
                X  = fmaf(st[i], hi, X);
            }
        }
        z[w] = fmaf(s2n[w], X, c2f[w] * fmaf(-2.0f, S1, 1.0f));
    }

    // logits + softmax (no max-subtraction; |logits| small)
    float e[6];
    float sum = 0.0f;
#pragma unroll
    for (int j = 0; j < 6; ++j) {
        float a = sb[j];
        a = fmaf(z[0], sW[j * 4 + 0], a);
        a = fmaf(z[1], sW[j * 4 + 1], a);
        a = fmaf(z[2], sW[j * 4 + 2], a);
        a = fmaf(z[3], sW[j * 4 + 3], a);
        e[j] = __expf(a);
        sum += e[j];
    }
    const float inv = __builtin_amdgcn_rcpf(sum);

    // Stage to LDS, then fully-coalesced float4 stores.
#pragma unroll
    for (int j = 0; j < 6; ++j) so[tid * 6 + j] = e[j] * inv;
    __syncthreads();

    const float4* so4 = reinterpret_cast<const float4*>(so);
    float4* out4 = reinterpret_cast<float4*>(out);
    const int base   = blockIdx.x * 384;      // 256*6/4
    const int total4 = B + (B >> 1);          // B*6/4, B=1e6 -> 1.5e6 (fits int)
#pragma unroll
    for (int k = 0; k < 2; ++k) {
        int idx = tid + k * 256;
        if (idx < 384 && base + idx < total4)
            out4[base + idx] = so4[idx];
    }
}

extern "C" void kernel_launch(void* const* d_in, const int* in_sizes, int n_in,
                              void* d_out, int out_size, void* d_ws, size_t ws_size,
                              hipStream_t stream) {
    const float* x    = (const float*)d_in[0];   // (B,4)
    const float* qw   = (const float*)d_in[1];   // (3,4)
    const float* W    = (const float*)d_in[2];   // (6,4)
    const float* bias = (const float*)d_in[3];   // (6,)
    float* out = (float*)d_out;

    const int B = in_sizes[0] / 4;
    const int blocks = (B + 255) / 256;
    qnn_kernel<<<blocks, 256, 0, stream>>>(x, qw, W, bias, out, B);
}